// Round 16
// baseline (309.137 us; speedup 1.0000x reference)
//
#include <hip/hip_runtime.h>

#define DEVI __device__ __forceinline__

typedef __attribute__((ext_vector_type(8))) short bf16x8;
typedef __attribute__((ext_vector_type(4))) float f32x4;
typedef __attribute__((ext_vector_type(16))) float f32x16;

DEVI ushort f2bf(float f) {
  union { float f; unsigned u; } v; v.f = f;
  unsigned u = v.u;
  unsigned r = (u + 0x7FFFu + ((u >> 16) & 1u)) >> 16;
  return (ushort)r;
}
DEVI float bf2f(ushort h) {
  union { unsigned u; float f; } v; v.u = ((unsigned)h) << 16;
  return v.f;
}
DEVI unsigned pkbf(float lo, float hi) {
  unsigned r;
  asm("v_cvt_pk_bf16_f32 %0, %1, %2" : "=v"(r) : "v"(lo), "v"(hi));
  return r;
}
DEVI float exp2v(float x) {
#if __has_builtin(__builtin_amdgcn_exp2f)
  return __builtin_amdgcn_exp2f(x);
#else
  return exp2f(x);
#endif
}

DEVI void gload_lds16(const ushort* g, ushort* l) {
  __builtin_amdgcn_global_load_lds((const __attribute__((address_space(1))) void*)g,
                                   (__attribute__((address_space(3))) void*)l, 16, 0, 0);
}

// bijective XCD swizzle for 2D grids with nwg % 8 == 0
DEVI void xcd_swz(int& bx, int& by) {
  const int nx = gridDim.x;
  const int flat = blockIdx.x + blockIdx.y * nx;
  const int cpx = (nx * gridDim.y) >> 3;
  const int swz = (flat & 7) * cpx + (flat >> 3);
  bx = swz % nx;
  by = swz / nx;
}

// ---------------- prep: cast x -> bf16; transpose+cast W_qkv, W_out ----------------
__global__ __launch_bounds__(256) void prep(const float* __restrict__ x,
                                            ushort* __restrict__ xb,
                                            const float* __restrict__ Wq,
                                            ushort* __restrict__ wtq,
                                            const float* __restrict__ Wo,
                                            ushort* __restrict__ wto) {
  __shared__ ushort tile[64][65];
  const int bid = blockIdx.x, t = threadIdx.x;
  if (bid < 4096) {
    int i = bid * 256 + t;
    const float4 v = ((const float4*)x)[i];
    uint2 o;
    o.x = (unsigned)f2bf(v.x) | ((unsigned)f2bf(v.y) << 16);
    o.y = (unsigned)f2bf(v.z) | ((unsigned)f2bf(v.w) << 16);
    ((uint2*)xb)[i] = o;
    return;
  }
  const float* in;
  ushort* out;
  int R, Cc, bx, by;
  if (bid < 4864) {
    in = Wq; out = wtq; R = 1024; Cc = 3072;
    bx = (bid - 4096) % 48; by = (bid - 4096) / 48;
  } else {
    in = Wo; out = wto; R = 1024; Cc = 1024;
    bx = (bid - 4864) % 16; by = (bid - 4864) / 16;
  }
  const int r0 = by * 64, c0 = bx * 64;
  for (int i = 0; i < 16; ++i) {
    int rr = i * 4 + (t >> 6), cc = t & 63;
    tile[rr][cc] = f2bf(in[(size_t)(r0 + rr) * Cc + c0 + cc]);
  }
  __syncthreads();
  for (int i = 0; i < 16; ++i) {
    int cc = i * 4 + (t >> 6), rr = t & 63;
    out[(size_t)(c0 + cc) * R + r0 + rr] = tile[rr][cc];
  }
}

// ---------------- QKV GEMM: 128x192x64 tile, 4 waves, 2 blocks/CU (R15) ----------------
__global__ __launch_bounds__(256, 2) void gemm_qkv(const ushort* __restrict__ A,
                                                   const ushort* __restrict__ Bt,
                                                   const float* __restrict__ bias,
                                                   ushort* __restrict__ O) {
  __shared__ ushort lds[2 * 20480];
  const int tid = threadIdx.x;
  const int w = tid >> 6, l = tid & 63;
  const int flat = blockIdx.x;
  const int xcd = flat & 7, slot = flat >> 3;
  const int bm = (xcd >> 1) * 8 + (slot >> 3);
  const int bn = (xcd & 1) * 8 + (slot & 7);
  const int m0 = bm * 128, n0 = bn * 192;
  const int wn = w * 48;
  const int lc = l & 15, lg = l >> 4;

  const int lrow = l >> 3;
  const int lcol = ((l & 7) ^ lrow) * 8;
  const ushort* pA[4];
  const ushort* pB[6];
#pragma unroll
  for (int i = 0; i < 4; ++i)
    pA[i] = A + (size_t)(m0 + (w * 4 + i) * 8 + lrow) * 1024 + lcol;
#pragma unroll
  for (int i = 0; i < 6; ++i)
    pB[i] = Bt + (size_t)(n0 + (w * 6 + i) * 8 + lrow) * 1024 + lcol;

  ushort* cur = lds;
  ushort* nxt = lds + 20480;

#pragma unroll
  for (int i = 0; i < 4; ++i) gload_lds16(pA[i], cur + (w * 4 + i) * 512);
#pragma unroll
  for (int i = 0; i < 6; ++i) gload_lds16(pB[i], cur + 8192 + (w * 6 + i) * 512);
  asm volatile("s_waitcnt vmcnt(0)" ::: "memory");
  __builtin_amdgcn_s_barrier();
  __builtin_amdgcn_sched_barrier(0);

  f32x4 acc[8][3];
#pragma unroll
  for (int i = 0; i < 8; ++i)
#pragma unroll
    for (int j = 0; j < 3; ++j) acc[i][j] = (f32x4){0.f, 0.f, 0.f, 0.f};

  const int aoff = lc * 64;
  const int boff = 8192 + (wn + lc) * 64;
  const int roph0 = ((0 + lg) ^ (lc & 7)) * 8;
  const int roph1 = ((4 + lg) ^ (lc & 7)) * 8;

  for (int t = 0; t < 16; ++t) {
    if (t < 15) {
#pragma unroll
      for (int i = 0; i < 4; ++i) gload_lds16(pA[i] + (t + 1) * 64, nxt + (w * 4 + i) * 512);
#pragma unroll
      for (int i = 0; i < 6; ++i) gload_lds16(pB[i] + (t + 1) * 64, nxt + 8192 + (w * 6 + i) * 512);
    }
    bf16x8 bfr[2][3];
#pragma unroll
    for (int fc = 0; fc < 3; ++fc) {
      bfr[0][fc] = *(const bf16x8*)(cur + boff + fc * 1024 + roph0);
      bfr[1][fc] = *(const bf16x8*)(cur + boff + fc * 1024 + roph1);
    }
    __builtin_amdgcn_s_setprio(1);
#pragma unroll
    for (int kc = 0; kc < 2; ++kc) {
      const int roph = kc ? roph1 : roph0;
      bf16x8 af[8];
#pragma unroll
      for (int fr = 0; fr < 8; ++fr)
        af[fr] = *(const bf16x8*)(cur + aoff + fr * 1024 + roph);
#pragma unroll
      for (int fr = 0; fr < 8; ++fr)
#pragma unroll
        for (int fc = 0; fc < 3; ++fc)
          acc[fr][fc] = __builtin_amdgcn_mfma_f32_16x16x32_bf16(af[fr], bfr[kc][fc], acc[fr][fc], 0, 0, 0);
    }
    __builtin_amdgcn_s_setprio(0);
    if (t < 15) {
      asm volatile("s_waitcnt vmcnt(0) lgkmcnt(0)" ::: "memory");
      __builtin_amdgcn_s_barrier();
      __builtin_amdgcn_sched_barrier(0);
      ushort* tp = cur; cur = nxt; nxt = tp;
    }
  }

  const int lr = lg * 4;
#pragma unroll
  for (int fc = 0; fc < 3; ++fc) {
    const int col = n0 + wn + fc * 16 + lc;
    const float bv = bias[col];
    const int grp = col >> 10, hh = (col >> 6) & 15, dd = col & 63;
    if (grp < 2) {
      size_t base = (size_t)grp * (16 * 4096 * 64) + (size_t)hh * (4096 * 64) + dd;
#pragma unroll
      for (int fr = 0; fr < 8; ++fr)
#pragma unroll
        for (int r = 0; r < 4; ++r) {
          int row = m0 + fr * 16 + lr + r;
          O[base + (size_t)row * 64] = f2bf(acc[fr][fc][r] + bv);
        }
    } else {
      size_t base = (size_t)2 * (16 * 4096 * 64) + ((size_t)hh * 64 + dd) * 4096;
#pragma unroll
      for (int fr = 0; fr < 8; ++fr)
#pragma unroll
        for (int r = 0; r < 4; ++r) {
          int row = m0 + fr * 16 + lr + r;
          O[base + row] = f2bf(acc[fr][fc][r] + bv);
        }
    }
  }
}

// ---------------- out GEMM: A (MxK bf16) @ Bt (NxK)^T, fp32 out + bias ----------------
__global__ __launch_bounds__(256) void gemm_out(const ushort* __restrict__ A,
                                                const ushort* __restrict__ Bt,
                                                const float* __restrict__ bias,
                                                float* __restrict__ O,
                                                int M, int Nn, int K) {
  __shared__ ushort As[2][128 * 32];
  __shared__ ushort Bs[2][128 * 32];
  const int tid = threadIdx.x;
  const int w = tid >> 6, l = tid & 63;
  int bx, by;
  xcd_swz(bx, by);
  const int m0 = by * 128, n0 = bx * 128;
  const int wm = (w >> 1) * 64, wn = (w & 1) * 64;
  const int lc = l & 15, lg = l >> 4;

  f32x4 acc[4][4];
  for (int i = 0; i < 4; ++i)
    for (int j = 0; j < 4; ++j) acc[i][j] = (f32x4){0.f, 0.f, 0.f, 0.f};

  const int srow = w * 32 + (l >> 2);
  const int scol = (l & 3) * 8;
  const ushort* gA = A + (size_t)(m0 + srow) * K + scol;
  const ushort* gB = Bt + (size_t)(n0 + srow) * K + scol;

  for (int k0 = 0; k0 < K; k0 += 64) {
#pragma unroll
    for (int s = 0; s < 2; ++s) {
      gload_lds16(gA + k0 + 32 * s,                  &As[s][(w * 32 + 0) * 32]);
      gload_lds16(gA + k0 + 32 * s + (size_t)16 * K, &As[s][(w * 32 + 16) * 32]);
      gload_lds16(gB + k0 + 32 * s,                  &Bs[s][(w * 32 + 0) * 32]);
      gload_lds16(gB + k0 + 32 * s + (size_t)16 * K, &Bs[s][(w * 32 + 16) * 32]);
    }
    __syncthreads();
#pragma unroll
    for (int s = 0; s < 2; ++s) {
      bf16x8 af[4], bfr[4];
      for (int mi = 0; mi < 4; ++mi)
        af[mi] = *(const bf16x8*)(&As[s][(wm + mi * 16 + lc) * 32 + lg * 8]);
      for (int ni = 0; ni < 4; ++ni)
        bfr[ni] = *(const bf16x8*)(&Bs[s][(wn + ni * 16 + lc) * 32 + lg * 8]);
      for (int mi = 0; mi < 4; ++mi)
        for (int ni = 0; ni < 4; ++ni)
          acc[mi][ni] = __builtin_amdgcn_mfma_f32_16x16x32_bf16(af[mi], bfr[ni], acc[mi][ni], 0, 0, 0);
    }
    __syncthreads();
  }

  const int lr = lg * 4;
  for (int ni = 0; ni < 4; ++ni) {
    int col = n0 + wn + ni * 16 + lc;
    float bv = bias[col];
    for (int mi = 0; mi < 4; ++mi)
      for (int r = 0; r < 4; ++r)
        O[(size_t)(m0 + wm + mi * 16 + lr + r) * Nn + col] = acc[mi][ni][r] + bv;
  }
}

// ---------------- RMSNorm + RoPE on Q,K (in place, bf16 head-major (H,N,D)) ----------------
DEVI void nr_one(ushort* B, const float* g, size_t base, int h, int l16,
                 float c0a, float s0a, float c1a, float s1a, float extra) {
  unsigned u0 = *(const unsigned*)(B + base + 2 * l16);
  unsigned u1 = *(const unsigned*)(B + base + 32 + 2 * l16);
  float t00 = bf2f((ushort)u0), t01 = bf2f((ushort)(u0 >> 16));
  float t10 = bf2f((ushort)u1), t11 = bf2f((ushort)(u1 >> 16));
  float ss = t00 * t00 + t01 * t01 + t10 * t10 + t11 * t11;
  for (int d = 1; d < 16; d <<= 1) ss += __shfl_xor(ss, d, 16);
  float scl = 8.f / fmaxf(sqrtf(ss), 1e-12f);
  scl *= extra;
  float g00 = g[h * 64 + 2 * l16], g01 = g[h * 64 + 2 * l16 + 1];
  float g10 = g[h * 64 + 32 + 2 * l16], g11 = g[h * 64 + 33 + 2 * l16];
  float q00 = t00 * scl * g00, q01 = t01 * scl * g01;
  float q10 = t10 * scl * g10, q11 = t11 * scl * g11;
  float o00 = q00 * c0a - q01 * s0a, o01 = q00 * s0a + q01 * c0a;
  float o10 = q10 * c1a - q11 * s1a, o11 = q10 * s1a + q11 * c1a;
  *(unsigned*)(B + base + 2 * l16) = (unsigned)f2bf(o00) | ((unsigned)f2bf(o01) << 16);
  *(unsigned*)(B + base + 32 + 2 * l16) = (unsigned)f2bf(o10) | ((unsigned)f2bf(o11) << 16);
}

__global__ __launch_bounds__(256) void norm_rope(ushort* __restrict__ Qb,
                                                 ushort* __restrict__ Kb,
                                                 const int* __restrict__ coords,
                                                 const float* __restrict__ gq,
                                                 const float* __restrict__ gk) {
  const int n = blockIdx.x, t = threadIdx.x;
  const int h = t >> 4, l16 = t & 15;
  const float L2_10K_D10 = 1.3287712379549449f; // log2(10000)/10
  float c0a, s0a, c1a, s1a;
  {
    int p = l16;
    int j = p / 10, fi = p - j * 10;
    float freq = exp2f(-(float)fi * L2_10K_D10);
    float ang = (float)coords[n * 3 + j] * freq;
    c0a = cosf(ang); s0a = sinf(ang);
  }
  {
    int p = l16 + 16;
    if (p < 30) {
      int j = p / 10, fi = p - j * 10;
      float freq = exp2f(-(float)fi * L2_10K_D10);
      float ang = (float)coords[n * 3 + j] * freq;
      c1a = cosf(ang); s1a = sinf(ang);
    } else { c1a = 1.f; s1a = 0.f; }
  }
  const size_t base = ((size_t)h * 4096 + n) * 64;
  nr_one(Qb, gq, base, h, l16, c0a, s0a, c1a, s1a, 0.125f * 1.4426950408889634f);
  nr_one(Kb, gk, base, h, l16, c0a, s0a, c1a, s1a, 1.0f);
}

// ---------------- flash attention core step (no-shift exp2 softmax) ----------------
DEVI void attn_step(const bf16x8 (&ck)[8], const bf16x8 (&cv)[8], const bf16x8 (&qf)[4],
                    f32x16& o0, f32x16& o1, f32x4& rs) {
  f32x16 s0, s1;
#pragma unroll
  for (int r = 0; r < 16; ++r) { s0[r] = 0.f; s1[r] = 0.f; }
#pragma unroll
  for (int c = 0; c < 4; ++c) {
    s0 = __builtin_amdgcn_mfma_f32_32x32x16_bf16(ck[c],     qf[c], s0, 0, 0, 0);
    s1 = __builtin_amdgcn_mfma_f32_32x32x16_bf16(ck[c + 4], qf[c], s1, 0, 0, 0);
  }
#pragma unroll
  for (int r = 0; r < 16; ++r) { s0[r] = exp2v(s0[r]); }
#pragma unroll
  for (int r = 0; r < 16; ++r) { s1[r] = exp2v(s1[r]); }
#pragma unroll
  for (int r = 0; r < 16; r += 4) {
    rs[0] += s0[r] + s1[r];
    rs[1] += s0[r + 1] + s1[r + 1];
    rs[2] += s0[r + 2] + s1[r + 2];
    rs[3] += s0[r + 3] + s1[r + 3];
  }
  union { unsigned u[4]; bf16x8 v; } pb[4];
  {
    auto r0 = __builtin_amdgcn_permlane32_swap(pkbf(s0[0], s0[1]), pkbf(s0[4], s0[5]), false, false);
    auto r1 = __builtin_amdgcn_permlane32_swap(pkbf(s0[2], s0[3]), pkbf(s0[6], s0[7]), false, false);
    pb[0].u[0] = r0[0]; pb[0].u[1] = r1[0]; pb[0].u[2] = r0[1]; pb[0].u[3] = r1[1];
    auto r2 = __builtin_amdgcn_permlane32_swap(pkbf(s0[8], s0[9]), pkbf(s0[12], s0[13]), false, false);
    auto r3 = __builtin_amdgcn_permlane32_swap(pkbf(s0[10], s0[11]), pkbf(s0[14], s0[15]), false, false);
    pb[1].u[0] = r2[0]; pb[1].u[1] = r3[0]; pb[1].u[2] = r2[1]; pb[1].u[3] = r3[1];
    auto r4 = __builtin_amdgcn_permlane32_swap(pkbf(s1[0], s1[1]), pkbf(s1[4], s1[5]), false, false);
    auto r5 = __builtin_amdgcn_permlane32_swap(pkbf(s1[2], s1[3]), pkbf(s1[6], s1[7]), false, false);
    pb[2].u[0] = r4[0]; pb[2].u[1] = r5[0]; pb[2].u[2] = r4[1]; pb[2].u[3] = r5[1];
    auto r6 = __builtin_amdgcn_permlane32_swap(pkbf(s1[8], s1[9]), pkbf(s1[12], s1[13]), false, false);
    auto r7 = __builtin_amdgcn_permlane32_swap(pkbf(s1[10], s1[11]), pkbf(s1[14], s1[15]), false, false);
    pb[3].u[0] = r6[0]; pb[3].u[1] = r7[0]; pb[3].u[2] = r6[1]; pb[3].u[3] = r7[1];
  }
#pragma unroll
  for (int c = 0; c < 4; ++c) {
    o0 = __builtin_amdgcn_mfma_f32_32x32x16_bf16(cv[c],     pb[c].v, o0, 0, 0, 0);
    o1 = __builtin_amdgcn_mfma_f32_32x32x16_bf16(cv[c + 4], pb[c].v, o1, 0, 0, 0);
  }
}

// ---------------- split-KV flash attention: 2 halves, 4 blocks/CU ----------------
// Fixed-shift softmax => partial O and lsum over disjoint KV ranges ADD exactly
// (no max merge). grid (32,16,2) = 1024 blocks -> 4 blocks/CU, 4 waves/SIMD:
// independent blocks' barriers interleave, filling the drain bubbles that cap
// the 2-block/CU version at 76% pipe utilization.
__global__ __launch_bounds__(256, 4) void attn_split(const ushort* __restrict__ Qb,
                                                     const ushort* __restrict__ Kb,
                                                     const ushort* __restrict__ Vt,
                                                     float* __restrict__ Opart,
                                                     float* __restrict__ Lpart) {
  __shared__ ushort Ks[2][4096];
  __shared__ ushort Vs[2][4096];

  const int flat = blockIdx.x + (blockIdx.y << 5) + (blockIdx.z << 9);
  const int swz = (flat & 7) * 128 + (flat >> 3); // bijective, 1024 blocks
  const int bx = swz & 31, h = (swz >> 5) & 15, half = swz >> 9;
  const int kv0 = half * 2048;

  const int l = threadIdx.x & 63, w = threadIdx.x >> 6;
  const int q = l & 31, hi = l >> 5;
  const int q0 = bx * 128 + w * 32;

  const ushort* qrow = Qb + ((size_t)h * 4096 + q0 + q) * 64 + hi * 8;
  bf16x8 qf[4];
#pragma unroll
  for (int c = 0; c < 4; ++c) qf[c] = *(const bf16x8*)(qrow + 16 * c);

  f32x16 o0, o1;
#pragma unroll
  for (int r = 0; r < 16; ++r) { o0[r] = 0.f; o1[r] = 0.f; }
  f32x4 rs = (f32x4){0.f, 0.f, 0.f, 0.f};

  const ushort* gK = Kb + ((size_t)h * 4096 + kv0 + l) * 64 + 2 * w * 8;
  const ushort* gV = Vt + ((size_t)h * 64 + l) * 4096 + kv0 + 2 * w * 8;

  ushort* Kc = &Ks[0][0]; ushort* Vc = &Vs[0][0];
  ushort* Kn = &Ks[1][0]; ushort* Vn = &Vs[1][0];

  gload_lds16(gK, Kc + 2 * w * 512);
  gload_lds16(gK + 8, Kc + (2 * w + 1) * 512);
  gload_lds16(gV, Vc + 2 * w * 512);
  gload_lds16(gV + 8, Vc + (2 * w + 1) * 512);
  asm volatile("s_waitcnt vmcnt(0)" ::: "memory");
  __builtin_amdgcn_s_barrier();
  __builtin_amdgcn_sched_barrier(0);

  const int lbase = hi * 512 + q * 8;
  for (int t = 0; t < 31; ++t) {
    const ushort* sK = gK + (size_t)(t + 1) * 64 * 64;
    const ushort* sV = gV + (t + 1) * 64;
    gload_lds16(sK, Kn + 2 * w * 512);
    gload_lds16(sK + 8, Kn + (2 * w + 1) * 512);
    gload_lds16(sV, Vn + 2 * w * 512);
    gload_lds16(sV + 8, Vn + (2 * w + 1) * 512);

    bf16x8 k[8], v[8];
#pragma unroll
    for (int c = 0; c < 4; ++c) {
      k[c]     = *(const bf16x8*)(Kc + lbase + c * 1024);
      k[c + 4] = *(const bf16x8*)(Kc + lbase + c * 1024 + 256);
      v[c]     = *(const bf16x8*)(Vc + lbase + c * 1024);
      v[c + 4] = *(const bf16x8*)(Vc + lbase + c * 1024 + 256);
    }
    __builtin_amdgcn_s_setprio(1);
    attn_step(k, v, qf, o0, o1, rs);
    __builtin_amdgcn_s_setprio(0);

    asm volatile("s_waitcnt vmcnt(0) lgkmcnt(0)" ::: "memory");
    __builtin_amdgcn_s_barrier();
    __builtin_amdgcn_sched_barrier(0);
    ushort* tp;
    tp = Kc; Kc = Kn; Kn = tp;
    tp = Vc; Vc = Vn; Vn = tp;
  }
  {
    bf16x8 k[8], v[8];
#pragma unroll
    for (int c = 0; c < 4; ++c) {
      k[c]     = *(const bf16x8*)(Kc + lbase + c * 1024);
      k[c + 4] = *(const bf16x8*)(Kc + lbase + c * 1024 + 256);
      v[c]     = *(const bf16x8*)(Vc + lbase + c * 1024);
      v[c + 4] = *(const bf16x8*)(Vc + lbase + c * 1024 + 256);
    }
    attn_step(k, v, qf, o0, o1, rs);
  }

  // partial lsum for this half (exact: fixed shift -> additive across halves)
  float lsum = (rs[0] + rs[1]) + (rs[2] + rs[3]);
  lsum += __shfl_xor(lsum, 32);
  if (hi == 0) Lpart[(size_t)half * 65536 + h * 4096 + q0 + q] = lsum;

  // raw (un-normalized) partial O, f32
  float* orow = Opart + (size_t)half * (4096 * 1024) + (size_t)(q0 + q) * 1024 + h * 64;
#pragma unroll
  for (int dt = 0; dt < 2; ++dt) {
    const f32x16& oo = dt ? o1 : o0;
#pragma unroll
    for (int g = 0; g < 4; ++g)
#pragma unroll
      for (int p2 = 0; p2 < 2; ++p2) {
        int r = g * 4 + p2 * 2;
        float2 val = make_float2(oo[r], oo[r + 1]);
        *(float2*)(orow + dt * 32 + g * 8 + 4 * hi + p2 * 2) = val;
      }
  }
}

// combine: attnb = (O1 + O2) / (l1 + l2), bf16
__global__ __launch_bounds__(256) void attn_combine(const float* __restrict__ Opart,
                                                    const float* __restrict__ Lpart,
                                                    ushort* __restrict__ attnb) {
  const int idx = (blockIdx.x * 256 + threadIdx.x) * 8; // over 4096*1024
  const int n = idx >> 10, c0 = idx & 1023, h = c0 >> 6;
  const float inv = 1.f / (Lpart[h * 4096 + n] + Lpart[65536 + h * 4096 + n]);
  const float4* p1 = (const float4*)(Opart + idx);
  const float4* p2 = (const float4*)(Opart + (size_t)(4096 * 1024) + idx);
  float4 a0 = p1[0], a1 = p1[1], b0 = p2[0], b1 = p2[1];
  uint2 w0, w1;
  w0.x = pkbf((a0.x + b0.x) * inv, (a0.y + b0.y) * inv);
  w0.y = pkbf((a0.z + b0.z) * inv, (a0.w + b0.w) * inv);
  w1.x = pkbf((a1.x + b1.x) * inv, (a1.y + b1.y) * inv);
  w1.y = pkbf((a1.z + b1.z) * inv, (a1.w + b1.w) * inv);
  ((uint2*)(attnb + idx))[0] = w0;
  ((uint2*)(attnb + idx))[1] = w1;
}

// ---------------- single-pass attention (R15 fallback if ws too small) ----------------
__global__ __launch_bounds__(256, 2) void attn_fwd(const ushort* __restrict__ Qb,
                                                   const ushort* __restrict__ Kb,
                                                   const ushort* __restrict__ Vt,
                                                   ushort* __restrict__ attnb) {
  __shared__ ushort Ks[2][4096];
  __shared__ ushort Vs[2][4096];

  const int flat = blockIdx.x + (blockIdx.y << 5);
  const int swz = (flat & 7) * 64 + (flat >> 3);
  const int bx = swz & 31, h = swz >> 5;

  const int l = threadIdx.x & 63, w = threadIdx.x >> 6;
  const int q = l & 31, hi = l >> 5;
  const int q0 = bx * 128 + w * 32;

  const ushort* qrow = Qb + ((size_t)h * 4096 + q0 + q) * 64 + hi * 8;
  bf16x8 qf[4];
#pragma unroll
  for (int c = 0; c < 4; ++c) qf[c] = *(const bf16x8*)(qrow + 16 * c);

  f32x16 o0, o1;
#pragma unroll
  for (int r = 0; r < 16; ++r) { o0[r] = 0.f; o1[r] = 0.f; }
  f32x4 rs = (f32x4){0.f, 0.f, 0.f, 0.f};

  const ushort* gK = Kb + ((size_t)h * 4096 + l) * 64 + 2 * w * 8;
  const ushort* gV = Vt + ((size_t)h * 64 + l) * 4096 + 2 * w * 8;

  ushort* Kc = &Ks[0][0]; ushort* Vc = &Vs[0][0];
  ushort* Kn = &Ks[1][0]; ushort* Vn = &Vs[1][0];

  gload_lds16(gK, Kc + 2 * w * 512);
  gload_lds16(gK + 8, Kc + (2 * w + 1) * 512);
  gload_lds16(gV, Vc + 2 * w * 512);
  gload_lds16(gV + 8, Vc + (2 * w + 1) * 512);
  asm volatile("s_waitcnt vmcnt(0)" ::: "memory");
  __builtin_amdgcn_s_barrier();
  __builtin_amdgcn_sched_barrier(0);

  const int lbase = hi * 512 + q * 8;
  for (int t = 0; t < 63; ++t) {
    const ushort* sK = gK + (size_t)(t + 1) * 64 * 64;
    const ushort* sV = gV + (t + 1) * 64;
    gload_lds16(sK, Kn + 2 * w * 512);
    gload_lds16(sK + 8, Kn + (2 * w + 1) * 512);
    gload_lds16(sV, Vn + 2 * w * 512);
    gload_lds16(sV + 8, Vn + (2 * w + 1) * 512);

    bf16x8 k[8], v[8];
#pragma unroll
    for (int c = 0; c < 4; ++c) {
      k[c]     = *(const bf16x8*)(Kc + lbase + c * 1024);
      k[c + 4] = *(const bf16x8*)(Kc + lbase + c * 1024 + 256);
      v[c]     = *(const bf16x8*)(Vc + lbase + c * 1024);
      v[c + 4] = *(const bf16x8*)(Vc + lbase + c * 1024 + 256);
    }
    __builtin_amdgcn_s_setprio(1);
    attn_step(k, v, qf, o0, o1, rs);
    __builtin_amdgcn_s_setprio(0);

    asm volatile("s_waitcnt vmcnt(0) lgkmcnt(0)" ::: "memory");
    __builtin_amdgcn_s_barrier();
    __builtin_amdgcn_sched_barrier(0);
    ushort* tp;
    tp = Kc; Kc = Kn; Kn = tp;
    tp = Vc; Vc = Vn; Vn = tp;
  }
  {
    bf16x8 k[8], v[8];
#pragma unroll
    for (int c = 0; c < 4; ++c) {
      k[c]     = *(const bf16x8*)(Kc + lbase + c * 1024);
      k[c + 4] = *(const bf16x8*)(Kc + lbase + c * 1024 + 256);
      v[c]     = *(const bf16x8*)(Vc + lbase + c * 1024);
      v[c + 4] = *(const bf16x8*)(Vc + lbase + c * 1024 + 256);
    }
    attn_step(k, v, qf, o0, o1, rs);
  }

  float lsum = (rs[0] + rs[1]) + (rs[2] + rs[3]);
  lsum += __shfl_xor(lsum, 32);
  const float inv = 1.f / lsum;
  ushort* orow = attnb + (size_t)(q0 + q) * 1024 + h * 64;
#pragma unroll
  for (int dt = 0; dt < 2; ++dt) {
    const f32x16& oo = dt ? o1 : o0;
#pragma unroll
    for (int g = 0; g < 4; ++g)
#pragma unroll
      for (int p2 = 0; p2 < 2; ++p2) {
        int r = g * 4 + p2 * 2;
        unsigned pk = pkbf(oo[r] * inv, oo[r + 1] * inv);
        *(unsigned*)(orow + dt * 32 + g * 8 + 4 * hi + p2 * 2) = pk;
      }
  }
}

extern "C" void kernel_launch(void* const* d_in, const int* in_sizes, int n_in,
                              void* d_out, int out_size, void* d_ws, size_t ws_size,
                              hipStream_t stream) {
  const float* x      = (const float*)d_in[0];
  const int*   coords = (const int*)d_in[1];
  const float* W_qkv  = (const float*)d_in[2];
  const float* b_qkv  = (const float*)d_in[3];
  const float* gq     = (const float*)d_in[4];
  const float* gk     = (const float*)d_in[5];
  const float* W_out  = (const float*)d_in[6];
  const float* b_out  = (const float*)d_in[7];
  float* out = (float*)d_out;

  char* ws = (char*)d_ws;
  ushort* xb    = (ushort*)(ws);                       // 8 MiB
  ushort* wtqkv = (ushort*)(ws + (8u << 20));          // 6 MiB
  ushort* wtout = (ushort*)(ws + (14u << 20));         // 2 MiB
  ushort* Qb    = (ushort*)(ws + (16u << 20));         // 8 MiB (H,N,D)
  ushort* Kb    = (ushort*)(ws + (24u << 20));         // 8 MiB (H,N,D)
  ushort* Vt    = (ushort*)(ws + (32u << 20));         // 8 MiB (H,D,N)
  ushort* attnb = (ushort*)(ws + (40u << 20));         // 8 MiB (N,C)
  float*  Opart = (float*)(ws + (48u << 20));          // 32 MiB (2 halves f32)
  float*  Lpart = (float*)(ws + (80u << 20));          // 512 KiB -> total ~80.5 MiB

  prep<<<5120, 256, 0, stream>>>(x, xb, W_qkv, wtqkv, W_out, wtout);
  gemm_qkv<<<512, 256, 0, stream>>>(xb, wtqkv, b_qkv, Qb);
  norm_rope<<<4096, 256, 0, stream>>>(Qb, Kb, coords, gq, gk);
  if (ws_size >= ((size_t)81 << 20)) {
    attn_split<<<dim3(32, 16, 2), 256, 0, stream>>>(Qb, Kb, Vt, Opart, Lpart);
    attn_combine<<<16384, 256, 0, stream>>>(Opart, Lpart, attnb);
  } else {
    attn_fwd<<<dim3(32, 16), 256, 0, stream>>>(Qb, Kb, Vt, attnb);
  }
  gemm_out<<<dim3(8, 32), 256, 0, stream>>>(attnb, wtout, b_out, out, 4096, 1024, 1024);
}

// Round 17
// 153.195 us; speedup vs baseline: 2.0179x; 2.0179x over previous
//
#include <hip/hip_runtime.h>

#define DEVI __device__ __forceinline__

typedef __attribute__((ext_vector_type(8))) short bf16x8;
typedef __attribute__((ext_vector_type(4))) float f32x4;
typedef __attribute__((ext_vector_type(16))) float f32x16;

DEVI ushort f2bf(float f) {
  union { float f; unsigned u; } v; v.f = f;
  unsigned u = v.u;
  unsigned r = (u + 0x7FFFu + ((u >> 16) & 1u)) >> 16;
  return (ushort)r;
}
DEVI float bf2f(ushort h) {
  union { unsigned u; float f; } v; v.u = ((unsigned)h) << 16;
  return v.f;
}
DEVI unsigned pkbf(float lo, float hi) {
  unsigned r;
  asm("v_cvt_pk_bf16_f32 %0, %1, %2" : "=v"(r) : "v"(lo), "v"(hi));
  return r;
}
DEVI float exp2v(float x) {
#if __has_builtin(__builtin_amdgcn_exp2f)
  return __builtin_amdgcn_exp2f(x);
#else
  return exp2f(x);
#endif
}

DEVI void gload_lds16(const ushort* g, ushort* l) {
  __builtin_amdgcn_global_load_lds((const __attribute__((address_space(1))) void*)g,
                                   (__attribute__((address_space(3))) void*)l, 16, 0, 0);
}

// bijective XCD swizzle for 2D grids with nwg % 8 == 0
DEVI void xcd_swz(int& bx, int& by) {
  const int nx = gridDim.x;
  const int flat = blockIdx.x + blockIdx.y * nx;
  const int cpx = (nx * gridDim.y) >> 3;
  const int swz = (flat & 7) * cpx + (flat >> 3);
  bx = swz % nx;
  by = swz / nx;
}

// ---------------- prep: cast x -> bf16; transpose+cast W_qkv, W_out ----------------
__global__ __launch_bounds__(256) void prep(const float* __restrict__ x,
                                            ushort* __restrict__ xb,
                                            const float* __restrict__ Wq,
                                            ushort* __restrict__ wtq,
                                            const float* __restrict__ Wo,
                                            ushort* __restrict__ wto) {
  __shared__ ushort tile[64][65];
  const int bid = blockIdx.x, t = threadIdx.x;
  if (bid < 4096) {
    int i = bid * 256 + t;
    const float4 v = ((const float4*)x)[i];
    uint2 o;
    o.x = (unsigned)f2bf(v.x) | ((unsigned)f2bf(v.y) << 16);
    o.y = (unsigned)f2bf(v.z) | ((unsigned)f2bf(v.w) << 16);
    ((uint2*)xb)[i] = o;
    return;
  }
  const float* in;
  ushort* out;
  int R, Cc, bx, by;
  if (bid < 4864) {
    in = Wq; out = wtq; R = 1024; Cc = 3072;
    bx = (bid - 4096) % 48; by = (bid - 4096) / 48;
  } else {
    in = Wo; out = wto; R = 1024; Cc = 1024;
    bx = (bid - 4864) % 16; by = (bid - 4864) / 16;
  }
  const int r0 = by * 64, c0 = bx * 64;
  for (int i = 0; i < 16; ++i) {
    int rr = i * 4 + (t >> 6), cc = t & 63;
    tile[rr][cc] = f2bf(in[(size_t)(r0 + rr) * Cc + c0 + cc]);
  }
  __syncthreads();
  for (int i = 0; i < 16; ++i) {
    int cc = i * 4 + (t >> 6), rr = t & 63;
    out[(size_t)(c0 + cc) * R + r0 + rr] = tile[rr][cc];
  }
}

// ---------------- QKV GEMM: 128x192x64 tile, 4 waves, 2 blocks/CU ----------------
// Swizzled LDS (chunk phys = logical ^ (row&7), both-sides involution).
__global__ __launch_bounds__(256, 2) void gemm_qkv(const ushort* __restrict__ A,
                                                   const ushort* __restrict__ Bt,
                                                   const float* __restrict__ bias,
                                                   ushort* __restrict__ O) {
  __shared__ ushort lds[2 * 20480]; // per buf: A 128x64 (8192) + B 192x64 (12288)
  const int tid = threadIdx.x;
  const int w = tid >> 6, l = tid & 63;
  const int flat = blockIdx.x;
  const int xcd = flat & 7, slot = flat >> 3;
  const int bm = (xcd >> 1) * 8 + (slot >> 3);
  const int bn = (xcd & 1) * 8 + (slot & 7);
  const int m0 = bm * 128, n0 = bn * 192;
  const int wn = w * 48;
  const int lc = l & 15, lg = l >> 4;

  const int lrow = l >> 3;
  const int lcol = ((l & 7) ^ lrow) * 8;
  const ushort* pA[4];
  const ushort* pB[6];
#pragma unroll
  for (int i = 0; i < 4; ++i)
    pA[i] = A + (size_t)(m0 + (w * 4 + i) * 8 + lrow) * 1024 + lcol;
#pragma unroll
  for (int i = 0; i < 6; ++i)
    pB[i] = Bt + (size_t)(n0 + (w * 6 + i) * 8 + lrow) * 1024 + lcol;

  ushort* cur = lds;
  ushort* nxt = lds + 20480;

#pragma unroll
  for (int i = 0; i < 4; ++i) gload_lds16(pA[i], cur + (w * 4 + i) * 512);
#pragma unroll
  for (int i = 0; i < 6; ++i) gload_lds16(pB[i], cur + 8192 + (w * 6 + i) * 512);
  asm volatile("s_waitcnt vmcnt(0)" ::: "memory");
  __builtin_amdgcn_s_barrier();
  __builtin_amdgcn_sched_barrier(0);

  f32x4 acc[8][3];
#pragma unroll
  for (int i = 0; i < 8; ++i)
#pragma unroll
    for (int j = 0; j < 3; ++j) acc[i][j] = (f32x4){0.f, 0.f, 0.f, 0.f};

  const int aoff = lc * 64;
  const int boff = 8192 + (wn + lc) * 64;
  const int roph0 = ((0 + lg) ^ (lc & 7)) * 8;
  const int roph1 = ((4 + lg) ^ (lc & 7)) * 8;

  for (int t = 0; t < 16; ++t) {
    if (t < 15) {
#pragma unroll
      for (int i = 0; i < 4; ++i) gload_lds16(pA[i] + (t + 1) * 64, nxt + (w * 4 + i) * 512);
#pragma unroll
      for (int i = 0; i < 6; ++i) gload_lds16(pB[i] + (t + 1) * 64, nxt + 8192 + (w * 6 + i) * 512);
    }
    bf16x8 bfr[2][3];
#pragma unroll
    for (int fc = 0; fc < 3; ++fc) {
      bfr[0][fc] = *(const bf16x8*)(cur + boff + fc * 1024 + roph0);
      bfr[1][fc] = *(const bf16x8*)(cur + boff + fc * 1024 + roph1);
    }
    __builtin_amdgcn_s_setprio(1);
#pragma unroll
    for (int kc = 0; kc < 2; ++kc) {
      const int roph = kc ? roph1 : roph0;
      bf16x8 af[8];
#pragma unroll
      for (int fr = 0; fr < 8; ++fr)
        af[fr] = *(const bf16x8*)(cur + aoff + fr * 1024 + roph);
#pragma unroll
      for (int fr = 0; fr < 8; ++fr)
#pragma unroll
        for (int fc = 0; fc < 3; ++fc)
          acc[fr][fc] = __builtin_amdgcn_mfma_f32_16x16x32_bf16(af[fr], bfr[kc][fc], acc[fr][fc], 0, 0, 0);
    }
    __builtin_amdgcn_s_setprio(0);
    if (t < 15) {
      asm volatile("s_waitcnt vmcnt(0) lgkmcnt(0)" ::: "memory");
      __builtin_amdgcn_s_barrier();
      __builtin_amdgcn_sched_barrier(0);
      ushort* tp = cur; cur = nxt; nxt = tp;
    }
  }

  const int lr = lg * 4;
#pragma unroll
  for (int fc = 0; fc < 3; ++fc) {
    const int col = n0 + wn + fc * 16 + lc;
    const float bv = bias[col];
    const int grp = col >> 10, hh = (col >> 6) & 15, dd = col & 63;
    if (grp < 2) {
      size_t base = (size_t)grp * (16 * 4096 * 64) + (size_t)hh * (4096 * 64) + dd;
#pragma unroll
      for (int fr = 0; fr < 8; ++fr)
#pragma unroll
        for (int r = 0; r < 4; ++r) {
          int row = m0 + fr * 16 + lr + r;
          O[base + (size_t)row * 64] = f2bf(acc[fr][fc][r] + bv);
        }
    } else {
      size_t base = (size_t)2 * (16 * 4096 * 64) + ((size_t)hh * 64 + dd) * 4096;
#pragma unroll
      for (int fr = 0; fr < 8; ++fr)
#pragma unroll
        for (int r = 0; r < 4; ++r) {
          int row = m0 + fr * 16 + lr + r;
          O[base + row] = f2bf(acc[fr][fc][r] + bv);
        }
    }
  }
}

// ---------------- out GEMM: A (MxK bf16) @ Bt (NxK)^T, fp32 out + bias ----------------
__global__ __launch_bounds__(256) void gemm_out(const ushort* __restrict__ A,
                                                const ushort* __restrict__ Bt,
                                                const float* __restrict__ bias,
                                                float* __restrict__ O,
                                                int M, int Nn, int K) {
  __shared__ ushort As[2][128 * 32];
  __shared__ ushort Bs[2][128 * 32];
  const int tid = threadIdx.x;
  const int w = tid >> 6, l = tid & 63;
  int bx, by;
  xcd_swz(bx, by);
  const int m0 = by * 128, n0 = bx * 128;
  const int wm = (w >> 1) * 64, wn = (w & 1) * 64;
  const int lc = l & 15, lg = l >> 4;

  f32x4 acc[4][4];
  for (int i = 0; i < 4; ++i)
    for (int j = 0; j < 4; ++j) acc[i][j] = (f32x4){0.f, 0.f, 0.f, 0.f};

  const int srow = w * 32 + (l >> 2);
  const int scol = (l & 3) * 8;
  const ushort* gA = A + (size_t)(m0 + srow) * K + scol;
  const ushort* gB = Bt + (size_t)(n0 + srow) * K + scol;

  for (int k0 = 0; k0 < K; k0 += 64) {
#pragma unroll
    for (int s = 0; s < 2; ++s) {
      gload_lds16(gA + k0 + 32 * s,                  &As[s][(w * 32 + 0) * 32]);
      gload_lds16(gA + k0 + 32 * s + (size_t)16 * K, &As[s][(w * 32 + 16) * 32]);
      gload_lds16(gB + k0 + 32 * s,                  &Bs[s][(w * 32 + 0) * 32]);
      gload_lds16(gB + k0 + 32 * s + (size_t)16 * K, &Bs[s][(w * 32 + 16) * 32]);
    }
    __syncthreads();
#pragma unroll
    for (int s = 0; s < 2; ++s) {
      bf16x8 af[4], bfr[4];
      for (int mi = 0; mi < 4; ++mi)
        af[mi] = *(const bf16x8*)(&As[s][(wm + mi * 16 + lc) * 32 + lg * 8]);
      for (int ni = 0; ni < 4; ++ni)
        bfr[ni] = *(const bf16x8*)(&Bs[s][(wn + ni * 16 + lc) * 32 + lg * 8]);
      for (int mi = 0; mi < 4; ++mi)
        for (int ni = 0; ni < 4; ++ni)
          acc[mi][ni] = __builtin_amdgcn_mfma_f32_16x16x32_bf16(af[mi], bfr[ni], acc[mi][ni], 0, 0, 0);
    }
    __syncthreads();
  }

  const int lr = lg * 4;
  for (int ni = 0; ni < 4; ++ni) {
    int col = n0 + wn + ni * 16 + lc;
    float bv = bias[col];
    for (int mi = 0; mi < 4; ++mi)
      for (int r = 0; r < 4; ++r)
        O[(size_t)(m0 + wm + mi * 16 + lr + r) * Nn + col] = acc[mi][ni][r] + bv;
  }
}

// ---------------- RMSNorm + RoPE on Q,K (in place, bf16 head-major (H,N,D)) ----------------
DEVI void nr_one(ushort* B, const float* g, size_t base, int h, int l16,
                 float c0a, float s0a, float c1a, float s1a, float extra) {
  unsigned u0 = *(const unsigned*)(B + base + 2 * l16);
  unsigned u1 = *(const unsigned*)(B + base + 32 + 2 * l16);
  float t00 = bf2f((ushort)u0), t01 = bf2f((ushort)(u0 >> 16));
  float t10 = bf2f((ushort)u1), t11 = bf2f((ushort)(u1 >> 16));
  float ss = t00 * t00 + t01 * t01 + t10 * t10 + t11 * t11;
  for (int d = 1; d < 16; d <<= 1) ss += __shfl_xor(ss, d, 16);
  float scl = 8.f / fmaxf(sqrtf(ss), 1e-12f);
  scl *= extra;
  float g00 = g[h * 64 + 2 * l16], g01 = g[h * 64 + 2 * l16 + 1];
  float g10 = g[h * 64 + 32 + 2 * l16], g11 = g[h * 64 + 33 + 2 * l16];
  float q00 = t00 * scl * g00, q01 = t01 * scl * g01;
  float q10 = t10 * scl * g10, q11 = t11 * scl * g11;
  float o00 = q00 * c0a - q01 * s0a, o01 = q00 * s0a + q01 * c0a;
  float o10 = q10 * c1a - q11 * s1a, o11 = q10 * s1a + q11 * c1a;
  *(unsigned*)(B + base + 2 * l16) = (unsigned)f2bf(o00) | ((unsigned)f2bf(o01) << 16);
  *(unsigned*)(B + base + 32 + 2 * l16) = (unsigned)f2bf(o10) | ((unsigned)f2bf(o11) << 16);
}

__global__ __launch_bounds__(256) void norm_rope(ushort* __restrict__ Qb,
                                                 ushort* __restrict__ Kb,
                                                 const int* __restrict__ coords,
                                                 const float* __restrict__ gq,
                                                 const float* __restrict__ gk) {
  const int n = blockIdx.x, t = threadIdx.x;
  const int h = t >> 4, l16 = t & 15;
  const float L2_10K_D10 = 1.3287712379549449f; // log2(10000)/10
  float c0a, s0a, c1a, s1a;
  {
    int p = l16;
    int j = p / 10, fi = p - j * 10;
    float freq = exp2f(-(float)fi * L2_10K_D10);
    float ang = (float)coords[n * 3 + j] * freq;
    c0a = cosf(ang); s0a = sinf(ang);
  }
  {
    int p = l16 + 16;
    if (p < 30) {
      int j = p / 10, fi = p - j * 10;
      float freq = exp2f(-(float)fi * L2_10K_D10);
      float ang = (float)coords[n * 3 + j] * freq;
      c1a = cosf(ang); s1a = sinf(ang);
    } else { c1a = 1.f; s1a = 0.f; }
  }
  const size_t base = ((size_t)h * 4096 + n) * 64;
  nr_one(Qb, gq, base, h, l16, c0a, s0a, c1a, s1a, 0.125f * 1.4426950408889634f);
  nr_one(Kb, gk, base, h, l16, c0a, s0a, c1a, s1a, 1.0f);
}

// ---------------- flash attention (R8 skeleton), no-shift exp2 softmax ----------------
DEVI void attn_step(const bf16x8 (&ck)[8], const bf16x8 (&cv)[8], const bf16x8 (&qf)[4],
                    f32x16& o0, f32x16& o1, f32x4& rs) {
  f32x16 s0, s1;
#pragma unroll
  for (int r = 0; r < 16; ++r) { s0[r] = 0.f; s1[r] = 0.f; }
#pragma unroll
  for (int c = 0; c < 4; ++c) {
    s0 = __builtin_amdgcn_mfma_f32_32x32x16_bf16(ck[c],     qf[c], s0, 0, 0, 0);
    s1 = __builtin_amdgcn_mfma_f32_32x32x16_bf16(ck[c + 4], qf[c], s1, 0, 0, 0);
  }
#pragma unroll
  for (int r = 0; r < 16; ++r) { s0[r] = exp2v(s0[r]); }
#pragma unroll
  for (int r = 0; r < 16; ++r) { s1[r] = exp2v(s1[r]); }
#pragma unroll
  for (int r = 0; r < 16; r += 4) {
    rs[0] += s0[r] + s1[r];
    rs[1] += s0[r + 1] + s1[r + 1];
    rs[2] += s0[r + 2] + s1[r + 2];
    rs[3] += s0[r + 3] + s1[r + 3];
  }
  union { unsigned u[4]; bf16x8 v; } pb[4];
  {
    auto r0 = __builtin_amdgcn_permlane32_swap(pkbf(s0[0], s0[1]), pkbf(s0[4], s0[5]), false, false);
    auto r1 = __builtin_amdgcn_permlane32_swap(pkbf(s0[2], s0[3]), pkbf(s0[6], s0[7]), false, false);
    pb[0].u[0] = r0[0]; pb[0].u[1] = r1[0]; pb[0].u[2] = r0[1]; pb[0].u[3] = r1[1];
    auto r2 = __builtin_amdgcn_permlane32_swap(pkbf(s0[8], s0[9]), pkbf(s0[12], s0[13]), false, false);
    auto r3 = __builtin_amdgcn_permlane32_swap(pkbf(s0[10], s0[11]), pkbf(s0[14], s0[15]), false, false);
    pb[1].u[0] = r2[0]; pb[1].u[1] = r3[0]; pb[1].u[2] = r2[1]; pb[1].u[3] = r3[1];
    auto r4 = __builtin_amdgcn_permlane32_swap(pkbf(s1[0], s1[1]), pkbf(s1[4], s1[5]), false, false);
    auto r5 = __builtin_amdgcn_permlane32_swap(pkbf(s1[2], s1[3]), pkbf(s1[6], s1[7]), false, false);
    pb[2].u[0] = r4[0]; pb[2].u[1] = r5[0]; pb[2].u[2] = r4[1]; pb[2].u[3] = r5[1];
    auto r6 = __builtin_amdgcn_permlane32_swap(pkbf(s1[8], s1[9]), pkbf(s1[12], s1[13]), false, false);
    auto r7 = __builtin_amdgcn_permlane32_swap(pkbf(s1[10], s1[11]), pkbf(s1[14], s1[15]), false, false);
    pb[3].u[0] = r6[0]; pb[3].u[1] = r7[0]; pb[3].u[2] = r6[1]; pb[3].u[3] = r7[1];
  }
#pragma unroll
  for (int c = 0; c < 4; ++c) {
    o0 = __builtin_amdgcn_mfma_f32_32x32x16_bf16(cv[c],     pb[c].v, o0, 0, 0, 0);
    o1 = __builtin_amdgcn_mfma_f32_32x32x16_bf16(cv[c + 4], pb[c].v, o1, 0, 0, 0);
  }
}

__global__ __launch_bounds__(256, 2) void attn_fwd(const ushort* __restrict__ Qb,
                                                   const ushort* __restrict__ Kb,
                                                   const ushort* __restrict__ Vt,
                                                   ushort* __restrict__ attnb) {
  __shared__ ushort Ks[2][4096]; // 8 KB per buf: [chunk 0..7][row 0..63][8 elems]
  __shared__ ushort Vs[2][4096];

  const int flat = blockIdx.x + (blockIdx.y << 5);
  const int swz = (flat & 7) * 64 + (flat >> 3);
  const int bx = swz & 31, h = swz >> 5;

  const int l = threadIdx.x & 63, w = threadIdx.x >> 6;
  const int q = l & 31, hi = l >> 5;
  const int q0 = bx * 128 + w * 32;

  const ushort* qrow = Qb + ((size_t)h * 4096 + q0 + q) * 64 + hi * 8;
  bf16x8 qf[4];
#pragma unroll
  for (int c = 0; c < 4; ++c) qf[c] = *(const bf16x8*)(qrow + 16 * c);

  f32x16 o0, o1;
#pragma unroll
  for (int r = 0; r < 16; ++r) { o0[r] = 0.f; o1[r] = 0.f; }
  f32x4 rs = (f32x4){0.f, 0.f, 0.f, 0.f};

  const ushort* gK = Kb + ((size_t)h * 4096 + l) * 64 + 2 * w * 8;
  const ushort* gV = Vt + ((size_t)h * 64 + l) * 4096 + 2 * w * 8;

  ushort* Kc = &Ks[0][0]; ushort* Vc = &Vs[0][0];
  ushort* Kn = &Ks[1][0]; ushort* Vn = &Vs[1][0];

  gload_lds16(gK, Kc + 2 * w * 512);
  gload_lds16(gK + 8, Kc + (2 * w + 1) * 512);
  gload_lds16(gV, Vc + 2 * w * 512);
  gload_lds16(gV + 8, Vc + (2 * w + 1) * 512);
  asm volatile("s_waitcnt vmcnt(0)" ::: "memory");
  __builtin_amdgcn_s_barrier();
  __builtin_amdgcn_sched_barrier(0);

  const int lbase = hi * 512 + q * 8;
  for (int t = 0; t < 63; ++t) {
    const ushort* sK = gK + (size_t)(t + 1) * 64 * 64;
    const ushort* sV = gV + (t + 1) * 64;
    gload_lds16(sK, Kn + 2 * w * 512);
    gload_lds16(sK + 8, Kn + (2 * w + 1) * 512);
    gload_lds16(sV, Vn + 2 * w * 512);
    gload_lds16(sV + 8, Vn + (2 * w + 1) * 512);

    bf16x8 k[8], v[8];
#pragma unroll
    for (int c = 0; c < 4; ++c) {
      k[c]     = *(const bf16x8*)(Kc + lbase + c * 1024);
      k[c + 4] = *(const bf16x8*)(Kc + lbase + c * 1024 + 256);
      v[c]     = *(const bf16x8*)(Vc + lbase + c * 1024);
      v[c + 4] = *(const bf16x8*)(Vc + lbase + c * 1024 + 256);
    }
    __builtin_amdgcn_s_setprio(1);
    attn_step(k, v, qf, o0, o1, rs);
    __builtin_amdgcn_s_setprio(0);

    asm volatile("s_waitcnt vmcnt(0) lgkmcnt(0)" ::: "memory");
    __builtin_amdgcn_s_barrier();
    __builtin_amdgcn_sched_barrier(0);
    ushort* tp;
    tp = Kc; Kc = Kn; Kn = tp;
    tp = Vc; Vc = Vn; Vn = tp;
  }
  {
    bf16x8 k[8], v[8];
#pragma unroll
    for (int c = 0; c < 4; ++c) {
      k[c]     = *(const bf16x8*)(Kc + lbase + c * 1024);
      k[c + 4] = *(const bf16x8*)(Kc + lbase + c * 1024 + 256);
      v[c]     = *(const bf16x8*)(Vc + lbase + c * 1024);
      v[c + 4] = *(const bf16x8*)(Vc + lbase + c * 1024 + 256);
    }
    attn_step(k, v, qf, o0, o1, rs);
  }

  float lsum = (rs[0] + rs[1]) + (rs[2] + rs[3]);
  lsum += __shfl_xor(lsum, 32);
  const float inv = 1.f / lsum;
  ushort* orow = attnb + (size_t)(q0 + q) * 1024 + h * 64;
#pragma unroll
  for (int dt = 0; dt < 2; ++dt) {
    const f32x16& oo = dt ? o1 : o0;
#pragma unroll
    for (int g = 0; g < 4; ++g)
#pragma unroll
      for (int p2 = 0; p2 < 2; ++p2) {
        int r = g * 4 + p2 * 2;
        unsigned pk = pkbf(oo[r] * inv, oo[r + 1] * inv);
        *(unsigned*)(orow + dt * 32 + g * 8 + 4 * hi + p2 * 2) = pk;
      }
  }
}

extern "C" void kernel_launch(void* const* d_in, const int* in_sizes, int n_in,
                              void* d_out, int out_size, void* d_ws, size_t ws_size,
                              hipStream_t stream) {
  const float* x      = (const float*)d_in[0];
  const int*   coords = (const int*)d_in[1];
  const float* W_qkv  = (const float*)d_in[2];
  const float* b_qkv  = (const float*)d_in[3];
  const float* gq     = (const float*)d_in[4];
  const float* gk     = (const float*)d_in[5];
  const float* W_out  = (const float*)d_in[6];
  const float* b_out  = (const float*)d_in[7];
  float* out = (float*)d_out;

  char* ws = (char*)d_ws;
  ushort* xb    = (ushort*)(ws);                       // 8 MiB: x bf16 (4096x1024)
  ushort* wtqkv = (ushort*)(ws + (8u << 20));          // 6 MiB: W_qkv^T bf16 (3072x1024)
  ushort* wtout = (ushort*)(ws + (14u << 20));         // 2 MiB: W_out^T bf16 (1024x1024)
  ushort* Qb    = (ushort*)(ws + (16u << 20));         // 8 MiB (H,N,D)
  ushort* Kb    = (ushort*)(ws + (24u << 20));         // 8 MiB (H,N,D)
  ushort* Vt    = (ushort*)(ws + (32u << 20));         // 8 MiB (H,D,N) -- written by gemm_qkv
  ushort* attnb = (ushort*)(ws + (40u << 20));         // 8 MiB (N,C)  -> total 48 MiB

  prep<<<5120, 256, 0, stream>>>(x, xb, W_qkv, wtqkv, W_out, wtout);
  gemm_qkv<<<512, 256, 0, stream>>>(xb, wtqkv, b_qkv, Qb);
  norm_rope<<<4096, 256, 0, stream>>>(Qb, Kb, coords, gq, gk);
  attn_fwd<<<dim3(32, 16), 256, 0, stream>>>(Qb, Kb, Vt, attnb);
  gemm_out<<<dim3(8, 32), 256, 0, stream>>>(attnb, wtout, b_out, out, 4096, 1024, 1024);
}